// Round 2
// baseline (890.245 us; speedup 1.0000x reference)
//
#include <hip/hip_runtime.h>
#include <hip/hip_bf16.h>
#include <cstdint>

// Problem constants: N=4096 tokens, D=1024, H=2048, E=8, TOP_K=2
#define N_TOK 4096
#define DIM   1024
#define HID   2048
#define NE    8

typedef __bf16 bf16x8 __attribute__((ext_vector_type(8)));
typedef __bf16 bf16x4 __attribute__((ext_vector_type(4)));
typedef float  f32x4  __attribute__((ext_vector_type(4)));

// Async global->LDS DMA, 16B per lane. LDS dest = wave-uniform base + lane*16.
__device__ __forceinline__ void gload16(const void* g, void* l) {
    __builtin_amdgcn_global_load_lds(
        (const __attribute__((address_space(1))) void*)g,
        (__attribute__((address_space(3))) void*)l, 16, 0, 0);
}

// ---------------------------------------------------------------------------
// x fp32 -> bf16
// ---------------------------------------------------------------------------
__global__ void cvt_x_kernel(const float* __restrict__ x, __bf16* __restrict__ xb) {
    const int i = (blockIdx.x * 256 + threadIdx.x) * 4;
    float4 v = *(const float4*)&x[i];
    bf16x4 o = { (__bf16)v.x, (__bf16)v.y, (__bf16)v.z, (__bf16)v.w };
    *(bf16x4*)&xb[i] = o;
}

// ---------------------------------------------------------------------------
// Per-expert transpose + fp32->bf16: src [E][R][C] -> dst [E][C][R]
// ---------------------------------------------------------------------------
__global__ void transpose_cvt_kernel(const float* __restrict__ src, __bf16* __restrict__ dst,
                                     int R, int C) {
    const size_t eoff = (size_t)blockIdx.z * R * C;
    src += eoff; dst += eoff;
    __shared__ float t[32][33];
    const int r0 = blockIdx.x * 32, c0 = blockIdx.y * 32;
    const int tr = threadIdx.x >> 3;
    const int tc = (threadIdx.x & 7) * 4;
    float4 v = *(const float4*)&src[(size_t)(r0 + tr) * C + c0 + tc];
    t[tr][tc + 0] = v.x; t[tr][tc + 1] = v.y; t[tr][tc + 2] = v.z; t[tr][tc + 3] = v.w;
    __syncthreads();
    bf16x4 o;
    o[0] = (__bf16)t[tc + 0][tr];
    o[1] = (__bf16)t[tc + 1][tr];
    o[2] = (__bf16)t[tc + 2][tr];
    o[3] = (__bf16)t[tc + 3][tr];
    *(bf16x4*)&dst[(size_t)(c0 + tr) * R + r0 + tc] = o;
}

// ---------------------------------------------------------------------------
// Gating: fp32 logits, softmax, top-2 (strict > keeps lowest index).
// ---------------------------------------------------------------------------
__global__ void gate_kernel(const float* __restrict__ x, const float* __restrict__ gW,
                            const float* __restrict__ gb, int* __restrict__ top_idx,
                            float* __restrict__ top_gate, int* __restrict__ cnt) {
    const int tokn = blockIdx.x * 4 + (threadIdx.x >> 6);
    const int lane = threadIdx.x & 63;
    const float* xr = x + (size_t)tokn * DIM;
    float acc[NE] = {};
    for (int i = 0; i < DIM / 64; i++) {
        const int d = lane + i * 64;
        const float xv = xr[d];
        const float4 w0 = *(const float4*)&gW[d * NE];
        const float4 w1 = *(const float4*)&gW[d * NE + 4];
        acc[0] += xv * w0.x; acc[1] += xv * w0.y; acc[2] += xv * w0.z; acc[3] += xv * w0.w;
        acc[4] += xv * w1.x; acc[5] += xv * w1.y; acc[6] += xv * w1.z; acc[7] += xv * w1.w;
    }
#pragma unroll
    for (int e = 0; e < NE; e++)
#pragma unroll
        for (int s = 32; s > 0; s >>= 1)
            acc[e] += __shfl_down(acc[e], s, 64);
    if (lane == 0) {
        float lg[NE], p[NE];
        float mx = -1e30f;
#pragma unroll
        for (int e = 0; e < NE; e++) { lg[e] = acc[e] + gb[e]; mx = fmaxf(mx, lg[e]); }
        float s = 0.f;
#pragma unroll
        for (int e = 0; e < NE; e++) { p[e] = __expf(lg[e] - mx); s += p[e]; }
        const float inv = 1.f / s;
#pragma unroll
        for (int e = 0; e < NE; e++) p[e] *= inv;
        int i0 = 0; float p0 = p[0];
#pragma unroll
        for (int e = 1; e < NE; e++) if (p[e] > p0) { p0 = p[e]; i0 = e; }
        int i1 = -1; float p1 = -1.f;
#pragma unroll
        for (int e = 0; e < NE; e++) if (e != i0 && p[e] > p1) { p1 = p[e]; i1 = e; }
        top_idx[tokn * 2] = i0;  top_idx[tokn * 2 + 1] = i1;
        top_gate[tokn * 2] = p0; top_gate[tokn * 2 + 1] = p1;
        atomicAdd(&cnt[i0], 1);  atomicAdd(&cnt[i1], 1);
    }
}

__global__ void scan_kernel(const int* __restrict__ cnt, int* __restrict__ offs) {
    if (threadIdx.x == 0) {
        int s = 0;
        for (int e = 0; e < NE; e++) { offs[e] = s; s += cnt[e]; }
        offs[NE] = s;
    }
}

// row lists + inverse map (token -> its two rows)
__global__ void build_kernel(const int* __restrict__ top_idx, const int* __restrict__ offs,
                             int* __restrict__ run, int* __restrict__ row_token,
                             int* __restrict__ tok_row) {
    const int n = blockIdx.x * 256 + threadIdx.x;
    if (n >= N_TOK) return;
#pragma unroll
    for (int k = 0; k < 2; k++) {
        const int e = top_idx[n * 2 + k];
        const int pos = atomicAdd(&run[e], 1);
        const int r = offs[e] + pos;
        row_token[r] = n;
        tok_row[n * 2 + k] = r;
    }
}

// ---------------------------------------------------------------------------
// Grouped GEMM1: h[r] = relu(x[tok(r)] @ W1t[e] + b1[e]), bf16 out.
// m97 structure: 128x128 tile, BK=32, global_load_lds(16B), LDS [q][128][8].
// ---------------------------------------------------------------------------
__global__ __launch_bounds__(256, 2) void gemm1_kernel(
    const __bf16* __restrict__ xb, const __bf16* __restrict__ w1t,
    const float* __restrict__ b1, const int* __restrict__ cnt,
    const int* __restrict__ offs, const int* __restrict__ row_token,
    __bf16* __restrict__ h) {
    const int e  = blockIdx.x >> 5;
    const int mt = blockIdx.x & 31;
    const int ce = cnt[e];
    if (mt * 128 >= ce) return;
    const int off_e = offs[e];
    const int n0 = blockIdx.y * 128;

    __shared__ __bf16 lA[4096];   // [q][128][8] = 8 KB
    __shared__ __bf16 lB[4096];

    const int tid  = threadIdx.x;
    const int lane = tid & 63;
    const int wid  = tid >> 6;
    const int quad = lane >> 4;
    const int l16  = lane & 15;
    const int wm   = wid & 1;
    const int wn   = wid >> 1;

    // staging addresses: wave w loads q=w chunk, rows lane and 64+lane
    const int r0 = lane, r1 = 64 + lane;
    int g0 = off_e + mt * 128 + r0; g0 = g0 < 2 * N_TOK - 1 ? g0 : 2 * N_TOK - 1;
    int g1 = off_e + mt * 128 + r1; g1 = g1 < 2 * N_TOK - 1 ? g1 : 2 * N_TOK - 1;
    const int t0 = row_token[g0] & (N_TOK - 1);
    const int t1 = row_token[g1] & (N_TOK - 1);
    const __bf16* a0 = xb + (size_t)t0 * DIM + wid * 8;
    const __bf16* a1 = xb + (size_t)t1 * DIM + wid * 8;
    const __bf16* b0 = w1t + ((size_t)e * HID + n0 + r0) * DIM + wid * 8;
    const __bf16* b1p = w1t + ((size_t)e * HID + n0 + r1) * DIM + wid * 8;
    char* lA0 = (char*)lA + (wid * 2 + 0) * 1024;
    char* lA1 = (char*)lA + (wid * 2 + 1) * 1024;
    char* lB0 = (char*)lB + (wid * 2 + 0) * 1024;
    char* lB1 = (char*)lB + (wid * 2 + 1) * 1024;

    f32x4 acc[4][4] = {};

    for (int kk = 0; kk < DIM; kk += 32) {
        gload16(a0 + kk, lA0);
        gload16(a1 + kk, lA1);
        gload16(b0 + kk, lB0);
        gload16(b1p + kk, lB1);
        __syncthreads();
        bf16x8 af[4], bfr[4];
#pragma unroll
        for (int mi = 0; mi < 4; mi++)
            af[mi] = *(const bf16x8*)&lA[((quad << 7) + wm * 64 + mi * 16 + l16) * 8];
#pragma unroll
        for (int ni = 0; ni < 4; ni++)
            bfr[ni] = *(const bf16x8*)&lB[((quad << 7) + wn * 64 + ni * 16 + l16) * 8];
#pragma unroll
        for (int mi = 0; mi < 4; mi++)
#pragma unroll
            for (int ni = 0; ni < 4; ni++)
                acc[mi][ni] = __builtin_amdgcn_mfma_f32_16x16x32_bf16(af[mi], bfr[ni], acc[mi][ni], 0, 0, 0);
        __syncthreads();
    }

#pragma unroll
    for (int ni = 0; ni < 4; ni++) {
        const int col = n0 + wn * 64 + ni * 16 + l16;
        const float bias = b1[e * HID + col];
#pragma unroll
        for (int mi = 0; mi < 4; mi++) {
#pragma unroll
            for (int r = 0; r < 4; r++) {
                const int lr = wm * 64 + mi * 16 + quad * 4 + r;
                const int gm = mt * 128 + lr;
                if (gm < ce) {
                    float v = acc[mi][ni][r] + bias;
                    v = v > 0.f ? v : 0.f;
                    h[(size_t)(off_e + gm) * HID + col] = (__bf16)v;
                }
            }
        }
    }
}

// ---------------------------------------------------------------------------
// Grouped GEMM2: y[r] = h[r] @ W2t[e] + b2[e], fp32 out (no atomics).
// ---------------------------------------------------------------------------
__global__ __launch_bounds__(256, 2) void gemm2_kernel(
    const __bf16* __restrict__ h, const __bf16* __restrict__ w2t,
    const float* __restrict__ b2, const int* __restrict__ cnt,
    const int* __restrict__ offs, float* __restrict__ y) {
    const int e  = blockIdx.x >> 5;
    const int mt = blockIdx.x & 31;
    const int ce = cnt[e];
    if (mt * 128 >= ce) return;
    const int off_e = offs[e];
    const int n0 = blockIdx.y * 128;

    __shared__ __bf16 lA[4096];
    __shared__ __bf16 lB[4096];

    const int tid  = threadIdx.x;
    const int lane = tid & 63;
    const int wid  = tid >> 6;
    const int quad = lane >> 4;
    const int l16  = lane & 15;
    const int wm   = wid & 1;
    const int wn   = wid >> 1;

    const int r0 = lane, r1 = 64 + lane;
    int g0 = off_e + mt * 128 + r0; g0 = g0 < 2 * N_TOK - 1 ? g0 : 2 * N_TOK - 1;
    int g1 = off_e + mt * 128 + r1; g1 = g1 < 2 * N_TOK - 1 ? g1 : 2 * N_TOK - 1;
    const __bf16* a0 = h + (size_t)g0 * HID + wid * 8;
    const __bf16* a1 = h + (size_t)g1 * HID + wid * 8;
    const __bf16* b0 = w2t + ((size_t)e * DIM + n0 + r0) * HID + wid * 8;
    const __bf16* b1p = w2t + ((size_t)e * DIM + n0 + r1) * HID + wid * 8;
    char* lA0 = (char*)lA + (wid * 2 + 0) * 1024;
    char* lA1 = (char*)lA + (wid * 2 + 1) * 1024;
    char* lB0 = (char*)lB + (wid * 2 + 0) * 1024;
    char* lB1 = (char*)lB + (wid * 2 + 1) * 1024;

    f32x4 acc[4][4] = {};

    for (int kk = 0; kk < HID; kk += 32) {
        gload16(a0 + kk, lA0);
        gload16(a1 + kk, lA1);
        gload16(b0 + kk, lB0);
        gload16(b1p + kk, lB1);
        __syncthreads();
        bf16x8 af[4], bfr[4];
#pragma unroll
        for (int mi = 0; mi < 4; mi++)
            af[mi] = *(const bf16x8*)&lA[((quad << 7) + wm * 64 + mi * 16 + l16) * 8];
#pragma unroll
        for (int ni = 0; ni < 4; ni++)
            bfr[ni] = *(const bf16x8*)&lB[((quad << 7) + wn * 64 + ni * 16 + l16) * 8];
#pragma unroll
        for (int mi = 0; mi < 4; mi++)
#pragma unroll
            for (int ni = 0; ni < 4; ni++)
                acc[mi][ni] = __builtin_amdgcn_mfma_f32_16x16x32_bf16(af[mi], bfr[ni], acc[mi][ni], 0, 0, 0);
        __syncthreads();
    }

#pragma unroll
    for (int mi = 0; mi < 4; mi++) {
#pragma unroll
        for (int r = 0; r < 4; r++) {
            const int lr = wm * 64 + mi * 16 + quad * 4 + r;
            const int gm = mt * 128 + lr;
            if (gm < ce) {
#pragma unroll
                for (int ni = 0; ni < 4; ni++) {
                    const int col = n0 + wn * 64 + ni * 16 + l16;
                    y[(size_t)(off_e + gm) * DIM + col] = acc[mi][ni][r] + b2[e * DIM + col];
                }
            }
        }
    }
}

// out[n] = g0*y[r0] + g1*y[r1] — coalesced, one block per token row.
__global__ void combine_kernel(const float* __restrict__ y, const int* __restrict__ tok_row,
                               const float* __restrict__ top_gate, float* __restrict__ out) {
    const int n = blockIdx.x;
    const int d = threadIdx.x * 4;
    const int r0 = tok_row[n * 2], r1 = tok_row[n * 2 + 1];
    const float g0 = top_gate[n * 2], g1 = top_gate[n * 2 + 1];
    float4 a = *(const float4*)&y[(size_t)r0 * DIM + d];
    float4 b = *(const float4*)&y[(size_t)r1 * DIM + d];
    float4 o = { g0 * a.x + g1 * b.x, g0 * a.y + g1 * b.y,
                 g0 * a.z + g1 * b.z, g0 * a.w + g1 * b.w };
    *(float4*)&out[(size_t)n * DIM + d] = o;
}

// ---------------------------------------------------------------------------
extern "C" void kernel_launch(void* const* d_in, const int* in_sizes, int n_in,
                              void* d_out, int out_size, void* d_ws, size_t ws_size,
                              hipStream_t stream) {
    const float* x  = (const float*)d_in[0];
    const float* gW = (const float*)d_in[1];
    const float* gb = (const float*)d_in[2];
    const float* W1 = (const float*)d_in[3];
    const float* b1 = (const float*)d_in[4];
    const float* W2 = (const float*)d_in[5];
    const float* b2 = (const float*)d_in[6];
    float* out = (float*)d_out;

    char* ws = (char*)d_ws;
    // ws layout:
    //   [0, 8 MiB)    xb  : x bf16 [N][D]
    //   [8, 40 MiB)   w1t : W1^T bf16 [E][H][D]   (dead after gemm1)
    //   [8, 40 MiB)   y   : fp32 [2N][D]          (overlays w1t, written by gemm2)
    //   [40, 72 MiB)  w2t : W2^T bf16 [E][D][H]
    //   [72, 104 MiB) h   : bf16 [2N][H]
    //   [104 MiB..)   routing metadata
    __bf16* xb   = (__bf16*)(ws);
    __bf16* w1t  = (__bf16*)(ws + ((size_t)8  << 20));
    float*  ybuf = (float*) (ws + ((size_t)8  << 20));
    __bf16* w2t  = (__bf16*)(ws + ((size_t)40 << 20));
    __bf16* hbuf = (__bf16*)(ws + ((size_t)72 << 20));
    char* tail   = ws + ((size_t)104 << 20);
    int*   row_token = (int*)(tail);
    int*   tok_row   = (int*)(tail + 32768);
    int*   top_idx   = (int*)(tail + 65536);
    float* top_gate  = (float*)(tail + 98304);
    int*   cnt       = (int*)(tail + 131072);
    int*   offs      = cnt + 16;
    int*   run       = cnt + 32;

    hipMemsetAsync(cnt, 0, 256, stream);

    cvt_x_kernel<<<N_TOK * DIM / 4 / 256, 256, 0, stream>>>(x, xb);
    transpose_cvt_kernel<<<dim3(DIM / 32, HID / 32, NE), 256, 0, stream>>>(W1, w1t, DIM, HID);
    transpose_cvt_kernel<<<dim3(HID / 32, DIM / 32, NE), 256, 0, stream>>>(W2, w2t, HID, DIM);
    gate_kernel<<<N_TOK / 4, 256, 0, stream>>>(x, gW, gb, top_idx, top_gate, cnt);
    scan_kernel<<<1, 64, 0, stream>>>(cnt, offs);
    build_kernel<<<N_TOK / 256, 256, 0, stream>>>(top_idx, offs, run, row_token, tok_row);
    gemm1_kernel<<<dim3(NE * 32, HID / 128), 256, 0, stream>>>(xb, w1t, b1, cnt, offs, row_token, hbuf);
    gemm2_kernel<<<dim3(NE * 32, DIM / 128), 256, 0, stream>>>(hbuf, w2t, b2, cnt, offs, ybuf);
    combine_kernel<<<N_TOK, 256, 0, stream>>>(ybuf, tok_row, top_gate, out);
}

// Round 3
// 614.640 us; speedup vs baseline: 1.4484x; 1.4484x over previous
//
#include <hip/hip_runtime.h>
#include <hip/hip_bf16.h>
#include <cstdint>

// Problem constants: N=4096 tokens, D=1024, H=2048, E=8, TOP_K=2
#define N_TOK 4096
#define DIM   1024
#define HID   2048
#define NE    8

typedef __bf16 bf16x8 __attribute__((ext_vector_type(8)));
typedef __bf16 bf16x4 __attribute__((ext_vector_type(4)));
typedef float  f32x4  __attribute__((ext_vector_type(4)));

// Async global->LDS DMA, 16B/lane. LDS dest = wave-uniform base + lane*16.
__device__ __forceinline__ void gload16(const void* g, void* l) {
    __builtin_amdgcn_global_load_lds(
        (const __attribute__((address_space(1))) void*)g,
        (__attribute__((address_space(3))) void*)l, 16, 0, 0);
}

// ---------------------------------------------------------------------------
// x fp32 -> bf16
// ---------------------------------------------------------------------------
__global__ void cvt_x_kernel(const float* __restrict__ x, __bf16* __restrict__ xb) {
    const int i = (blockIdx.x * 256 + threadIdx.x) * 4;
    float4 v = *(const float4*)&x[i];
    bf16x4 o = { (__bf16)v.x, (__bf16)v.y, (__bf16)v.z, (__bf16)v.w };
    *(bf16x4*)&xb[i] = o;
}

// ---------------------------------------------------------------------------
// Per-expert transpose + fp32->bf16: src [E][R][C] -> dst [E][C][R]
// ---------------------------------------------------------------------------
__global__ void transpose_cvt_kernel(const float* __restrict__ src, __bf16* __restrict__ dst,
                                     int R, int C) {
    const size_t eoff = (size_t)blockIdx.z * R * C;
    src += eoff; dst += eoff;
    __shared__ float t[32][33];
    const int r0 = blockIdx.x * 32, c0 = blockIdx.y * 32;
    const int tr = threadIdx.x >> 3;
    const int tc = (threadIdx.x & 7) * 4;
    float4 v = *(const float4*)&src[(size_t)(r0 + tr) * C + c0 + tc];
    t[tr][tc + 0] = v.x; t[tr][tc + 1] = v.y; t[tr][tc + 2] = v.z; t[tr][tc + 3] = v.w;
    __syncthreads();
    bf16x4 o;
    o[0] = (__bf16)t[tc + 0][tr];
    o[1] = (__bf16)t[tc + 1][tr];
    o[2] = (__bf16)t[tc + 2][tr];
    o[3] = (__bf16)t[tc + 3][tr];
    *(bf16x4*)&dst[(size_t)(c0 + tr) * R + r0 + tc] = o;
}

// ---------------------------------------------------------------------------
// Gating: fp32 logits, softmax, top-2 (strict > keeps lowest index).
// ---------------------------------------------------------------------------
__global__ void gate_kernel(const float* __restrict__ x, const float* __restrict__ gW,
                            const float* __restrict__ gb, int* __restrict__ top_idx,
                            float* __restrict__ top_gate, int* __restrict__ cnt) {
    const int tokn = blockIdx.x * 4 + (threadIdx.x >> 6);
    const int lane = threadIdx.x & 63;
    const float* xr = x + (size_t)tokn * DIM;
    float acc[NE] = {};
    for (int i = 0; i < DIM / 64; i++) {
        const int d = lane + i * 64;
        const float xv = xr[d];
        const float4 w0 = *(const float4*)&gW[d * NE];
        const float4 w1 = *(const float4*)&gW[d * NE + 4];
        acc[0] += xv * w0.x; acc[1] += xv * w0.y; acc[2] += xv * w0.z; acc[3] += xv * w0.w;
        acc[4] += xv * w1.x; acc[5] += xv * w1.y; acc[6] += xv * w1.z; acc[7] += xv * w1.w;
    }
#pragma unroll
    for (int e = 0; e < NE; e++)
#pragma unroll
        for (int s = 32; s > 0; s >>= 1)
            acc[e] += __shfl_down(acc[e], s, 64);
    if (lane == 0) {
        float lg[NE], p[NE];
        float mx = -1e30f;
#pragma unroll
        for (int e = 0; e < NE; e++) { lg[e] = acc[e] + gb[e]; mx = fmaxf(mx, lg[e]); }
        float s = 0.f;
#pragma unroll
        for (int e = 0; e < NE; e++) { p[e] = __expf(lg[e] - mx); s += p[e]; }
        const float inv = 1.f / s;
#pragma unroll
        for (int e = 0; e < NE; e++) p[e] *= inv;
        int i0 = 0; float p0 = p[0];
#pragma unroll
        for (int e = 1; e < NE; e++) if (p[e] > p0) { p0 = p[e]; i0 = e; }
        int i1 = -1; float p1 = -1.f;
#pragma unroll
        for (int e = 0; e < NE; e++) if (e != i0 && p[e] > p1) { p1 = p[e]; i1 = e; }
        top_idx[tokn * 2] = i0;  top_idx[tokn * 2 + 1] = i1;
        top_gate[tokn * 2] = p0; top_gate[tokn * 2 + 1] = p1;
        atomicAdd(&cnt[i0], 1);  atomicAdd(&cnt[i1], 1);
    }
}

__global__ void scan_kernel(const int* __restrict__ cnt, int* __restrict__ offs) {
    if (threadIdx.x == 0) {
        int s = 0;
        for (int e = 0; e < NE; e++) { offs[e] = s; s += cnt[e]; }
        offs[NE] = s;
    }
}

__global__ void build_kernel(const int* __restrict__ top_idx, const int* __restrict__ offs,
                             int* __restrict__ run, int* __restrict__ row_token,
                             int* __restrict__ tok_row) {
    const int n = blockIdx.x * 256 + threadIdx.x;
    if (n >= N_TOK) return;
#pragma unroll
    for (int k = 0; k < 2; k++) {
        const int e = top_idx[n * 2 + k];
        const int pos = atomicAdd(&run[e], 1);
        const int r = offs[e] + pos;
        row_token[r] = n;
        tok_row[n * 2 + k] = r;
    }
}

// ---------------------------------------------------------------------------
// Grouped GEMM1: h[r] = relu(x[tok(r)] @ W1t[e] + b1[e]), bf16 out.
// 128x128 tile, BK=64, global_load_lds(16B) with XOR-swizzled LDS:
//   tile row = 128B (8 chunks of 16B); chunk c of row stored at slot c^(row&7).
//   DMA: 8 lanes cover one row's contiguous 128B (coalesced); fragment
//   ds_read_b128 lands 2-way bank-aliased (free).
// ---------------------------------------------------------------------------
__global__ __launch_bounds__(256, 2) void gemm1_kernel(
    const __bf16* __restrict__ xb, const __bf16* __restrict__ w1t,
    const float* __restrict__ b1, const int* __restrict__ cnt,
    const int* __restrict__ offs, const int* __restrict__ row_token,
    __bf16* __restrict__ h) {
    const int e  = blockIdx.x >> 5;
    const int mt = blockIdx.x & 31;
    const int ce = cnt[e];
    if (mt * 128 >= ce) return;
    const int off_e = offs[e];
    const int n0 = blockIdx.y * 128;

    __shared__ __bf16 lA[8192];   // 128 rows x 64 cols = 16KB, swizzled
    __shared__ __bf16 lB[8192];

    const int tid  = threadIdx.x;
    const int lane = tid & 63;
    const int wid  = tid >> 6;
    const int quad = lane >> 4;
    const int l16  = lane & 15;
    const int wm   = wid & 1;
    const int wn   = wid >> 1;

    // staging: DMA instr j (wave wid) covers rows (wid*4+j)*8 .. +7
    const int lrow = lane >> 3;              // row within 8-row group
    const int cch  = (lane & 7) ^ lrow;      // global 16B-chunk within row
    const __bf16* aros[4]; const __bf16* bros[4];
    char* ldsA[4]; char* ldsB[4];
#pragma unroll
    for (int j = 0; j < 4; j++) {
        const int row = (wid * 4 + j) * 8 + lrow;     // tile row 0..127
        int gr = off_e + mt * 128 + row;
        gr = gr < 2 * N_TOK - 1 ? gr : 2 * N_TOK - 1;
        const int tok = row_token[gr] & (N_TOK - 1);
        aros[j] = xb  + (size_t)tok * DIM + cch * 8;
        bros[j] = w1t + ((size_t)e * HID + n0 + row) * DIM + cch * 8;
        ldsA[j] = (char*)lA + (wid * 4 + j) * 1024;
        ldsB[j] = (char*)lB + (wid * 4 + j) * 1024;
    }

    f32x4 acc[4][4] = {};

    for (int kk = 0; kk < DIM; kk += 64) {
#pragma unroll
        for (int j = 0; j < 4; j++) gload16(aros[j] + kk, ldsA[j]);
#pragma unroll
        for (int j = 0; j < 4; j++) gload16(bros[j] + kk, ldsB[j]);
        __syncthreads();
#pragma unroll
        for (int hh = 0; hh < 2; hh++) {
            const int q4 = quad + hh * 4;
            const int sw = (q4 ^ (l16 & 7)) << 4;
            bf16x8 af[4], bfr[4];
#pragma unroll
            for (int mi = 0; mi < 4; mi++) {
                const int ar = wm * 64 + mi * 16 + l16;
                af[mi] = *(const bf16x8*)((const char*)lA + ar * 128 + sw);
            }
#pragma unroll
            for (int ni = 0; ni < 4; ni++) {
                const int br = wn * 64 + ni * 16 + l16;
                bfr[ni] = *(const bf16x8*)((const char*)lB + br * 128 + sw);
            }
#pragma unroll
            for (int mi = 0; mi < 4; mi++)
#pragma unroll
                for (int ni = 0; ni < 4; ni++)
                    acc[mi][ni] = __builtin_amdgcn_mfma_f32_16x16x32_bf16(af[mi], bfr[ni], acc[mi][ni], 0, 0, 0);
        }
        __syncthreads();
    }

#pragma unroll
    for (int ni = 0; ni < 4; ni++) {
        const int col = n0 + wn * 64 + ni * 16 + l16;
        const float bias = b1[e * HID + col];
#pragma unroll
        for (int mi = 0; mi < 4; mi++) {
#pragma unroll
            for (int r = 0; r < 4; r++) {
                const int lr = wm * 64 + mi * 16 + quad * 4 + r;
                const int gm = mt * 128 + lr;
                if (gm < ce) {
                    float v = acc[mi][ni][r] + bias;
                    v = v > 0.f ? v : 0.f;
                    h[(size_t)(off_e + gm) * HID + col] = (__bf16)v;
                }
            }
        }
    }
}

// ---------------------------------------------------------------------------
// Grouped GEMM2: y[r] = h[r] @ W2t[e] + b2[e], fp32 out (no atomics).
// Same structure as gemm1 (K = HID).
// ---------------------------------------------------------------------------
__global__ __launch_bounds__(256, 2) void gemm2_kernel(
    const __bf16* __restrict__ h, const __bf16* __restrict__ w2t,
    const float* __restrict__ b2, const int* __restrict__ cnt,
    const int* __restrict__ offs, float* __restrict__ y) {
    const int e  = blockIdx.x >> 5;
    const int mt = blockIdx.x & 31;
    const int ce = cnt[e];
    if (mt * 128 >= ce) return;
    const int off_e = offs[e];
    const int n0 = blockIdx.y * 128;

    __shared__ __bf16 lA[8192];
    __shared__ __bf16 lB[8192];

    const int tid  = threadIdx.x;
    const int lane = tid & 63;
    const int wid  = tid >> 6;
    const int quad = lane >> 4;
    const int l16  = lane & 15;
    const int wm   = wid & 1;
    const int wn   = wid >> 1;

    const int lrow = lane >> 3;
    const int cch  = (lane & 7) ^ lrow;
    const __bf16* aros[4]; const __bf16* bros[4];
    char* ldsA[4]; char* ldsB[4];
#pragma unroll
    for (int j = 0; j < 4; j++) {
        const int row = (wid * 4 + j) * 8 + lrow;
        int gr = off_e + mt * 128 + row;
        gr = gr < 2 * N_TOK - 1 ? gr : 2 * N_TOK - 1;   // clamp inside h buffer
        aros[j] = h   + (size_t)gr * HID + cch * 8;
        bros[j] = w2t + ((size_t)e * DIM + n0 + row) * HID + cch * 8;
        ldsA[j] = (char*)lA + (wid * 4 + j) * 1024;
        ldsB[j] = (char*)lB + (wid * 4 + j) * 1024;
    }

    f32x4 acc[4][4] = {};

    for (int kk = 0; kk < HID; kk += 64) {
#pragma unroll
        for (int j = 0; j < 4; j++) gload16(aros[j] + kk, ldsA[j]);
#pragma unroll
        for (int j = 0; j < 4; j++) gload16(bros[j] + kk, ldsB[j]);
        __syncthreads();
#pragma unroll
        for (int hh = 0; hh < 2; hh++) {
            const int q4 = quad + hh * 4;
            const int sw = (q4 ^ (l16 & 7)) << 4;
            bf16x8 af[4], bfr[4];
#pragma unroll
            for (int mi = 0; mi < 4; mi++) {
                const int ar = wm * 64 + mi * 16 + l16;
                af[mi] = *(const bf16x8*)((const char*)lA + ar * 128 + sw);
            }
#pragma unroll
            for (int ni = 0; ni < 4; ni++) {
                const int br = wn * 64 + ni * 16 + l16;
                bfr[ni] = *(const bf16x8*)((const char*)lB + br * 128 + sw);
            }
#pragma unroll
            for (int mi = 0; mi < 4; mi++)
#pragma unroll
                for (int ni = 0; ni < 4; ni++)
                    acc[mi][ni] = __builtin_amdgcn_mfma_f32_16x16x32_bf16(af[mi], bfr[ni], acc[mi][ni], 0, 0, 0);
        }
        __syncthreads();
    }

#pragma unroll
    for (int mi = 0; mi < 4; mi++) {
#pragma unroll
        for (int r = 0; r < 4; r++) {
            const int lr = wm * 64 + mi * 16 + quad * 4 + r;
            const int gm = mt * 128 + lr;
            if (gm < ce) {
#pragma unroll
                for (int ni = 0; ni < 4; ni++) {
                    const int col = n0 + wn * 64 + ni * 16 + l16;
                    y[(size_t)(off_e + gm) * DIM + col] = acc[mi][ni][r] + b2[e * DIM + col];
                }
            }
        }
    }
}

// out[n] = g0*y[r0] + g1*y[r1] — coalesced, one block per token row.
__global__ void combine_kernel(const float* __restrict__ y, const int* __restrict__ tok_row,
                               const float* __restrict__ top_gate, float* __restrict__ out) {
    const int n = blockIdx.x;
    const int d = threadIdx.x * 4;
    const int r0 = tok_row[n * 2], r1 = tok_row[n * 2 + 1];
    const float g0 = top_gate[n * 2], g1 = top_gate[n * 2 + 1];
    float4 a = *(const float4*)&y[(size_t)r0 * DIM + d];
    float4 b = *(const float4*)&y[(size_t)r1 * DIM + d];
    float4 o = { g0 * a.x + g1 * b.x, g0 * a.y + g1 * b.y,
                 g0 * a.z + g1 * b.z, g0 * a.w + g1 * b.w };
    *(float4*)&out[(size_t)n * DIM + d] = o;
}

// ---------------------------------------------------------------------------
extern "C" void kernel_launch(void* const* d_in, const int* in_sizes, int n_in,
                              void* d_out, int out_size, void* d_ws, size_t ws_size,
                              hipStream_t stream) {
    const float* x  = (const float*)d_in[0];
    const float* gW = (const float*)d_in[1];
    const float* gb = (const float*)d_in[2];
    const float* W1 = (const float*)d_in[3];
    const float* b1 = (const float*)d_in[4];
    const float* W2 = (const float*)d_in[5];
    const float* b2 = (const float*)d_in[6];
    float* out = (float*)d_out;

    char* ws = (char*)d_ws;
    // ws layout:
    //   [0, 8 MiB)    xb  : x bf16 [N][D]
    //   [8, 40 MiB)   w1t : W1^T bf16 [E][H][D]   (dead after gemm1)
    //   [8, 40 MiB)   y   : fp32 [2N][D]          (overlays w1t)
    //   [40, 72 MiB)  w2t : W2^T bf16 [E][D][H]
    //   [72, 104 MiB) h   : bf16 [2N][H]
    //   [104 MiB..)   routing metadata
    __bf16* xb   = (__bf16*)(ws);
    __bf16* w1t  = (__bf16*)(ws + ((size_t)8  << 20));
    float*  ybuf = (float*) (ws + ((size_t)8  << 20));
    __bf16* w2t  = (__bf16*)(ws + ((size_t)40 << 20));
    __bf16* hbuf = (__bf16*)(ws + ((size_t)72 << 20));
    char* tail   = ws + ((size_t)104 << 20);
    int*   row_token = (int*)(tail);
    int*   tok_row   = (int*)(tail + 32768);
    int*   top_idx   = (int*)(tail + 65536);
    float* top_gate  = (float*)(tail + 98304);
    int*   cnt       = (int*)(tail + 131072);
    int*   offs      = cnt + 16;
    int*   run       = cnt + 32;

    hipMemsetAsync(cnt, 0, 256, stream);

    cvt_x_kernel<<<N_TOK * DIM / 4 / 256, 256, 0, stream>>>(x, xb);
    transpose_cvt_kernel<<<dim3(DIM / 32, HID / 32, NE), 256, 0, stream>>>(W1, w1t, DIM, HID);
    transpose_cvt_kernel<<<dim3(HID / 32, DIM / 32, NE), 256, 0, stream>>>(W2, w2t, HID, DIM);
    gate_kernel<<<N_TOK / 4, 256, 0, stream>>>(x, gW, gb, top_idx, top_gate, cnt);
    scan_kernel<<<1, 64, 0, stream>>>(cnt, offs);
    build_kernel<<<N_TOK / 256, 256, 0, stream>>>(top_idx, offs, run, row_token, tok_row);
    gemm1_kernel<<<dim3(NE * 32, HID / 128), 256, 0, stream>>>(xb, w1t, b1, cnt, offs, row_token, hbuf);
    gemm2_kernel<<<dim3(NE * 32, DIM / 128), 256, 0, stream>>>(hbuf, w2t, b2, cnt, offs, ybuf);
    combine_kernel<<<N_TOK, 256, 0, stream>>>(ybuf, tok_row, top_gate, out);
}

// Round 4
// 430.872 us; speedup vs baseline: 2.0661x; 1.4265x over previous
//
#include <hip/hip_runtime.h>
#include <hip/hip_bf16.h>
#include <cstdint>

// Problem constants: N=4096 tokens, D=1024, H=2048, E=8, TOP_K=2
#define N_TOK 4096
#define DIM   1024
#define HID   2048
#define NE    8

typedef __bf16 bf16x8 __attribute__((ext_vector_type(8)));
typedef __bf16 bf16x4 __attribute__((ext_vector_type(4)));
typedef float  f32x4  __attribute__((ext_vector_type(4)));

// Async global->LDS DMA, 16B/lane. LDS dest = wave-uniform base + lane*16.
__device__ __forceinline__ void gload16(const void* g, void* l) {
    __builtin_amdgcn_global_load_lds(
        (const __attribute__((address_space(1))) void*)g,
        (__attribute__((address_space(3))) void*)l, 16, 0, 0);
}

// ---------------------------------------------------------------------------
// x fp32 -> bf16
// ---------------------------------------------------------------------------
__global__ void cvt_x_kernel(const float* __restrict__ x, __bf16* __restrict__ xb) {
    const int i = (blockIdx.x * 256 + threadIdx.x) * 4;
    float4 v = *(const float4*)&x[i];
    bf16x4 o = { (__bf16)v.x, (__bf16)v.y, (__bf16)v.z, (__bf16)v.w };
    *(bf16x4*)&xb[i] = o;
}

// ---------------------------------------------------------------------------
// Per-expert transpose + fp32->bf16: src [E][R][C] -> dst [E][C][R]
// ---------------------------------------------------------------------------
__global__ void transpose_cvt_kernel(const float* __restrict__ src, __bf16* __restrict__ dst,
                                     int R, int C) {
    const size_t eoff = (size_t)blockIdx.z * R * C;
    src += eoff; dst += eoff;
    __shared__ float t[32][33];
    const int r0 = blockIdx.x * 32, c0 = blockIdx.y * 32;
    const int tr = threadIdx.x >> 3;
    const int tc = (threadIdx.x & 7) * 4;
    float4 v = *(const float4*)&src[(size_t)(r0 + tr) * C + c0 + tc];
    t[tr][tc + 0] = v.x; t[tr][tc + 1] = v.y; t[tr][tc + 2] = v.z; t[tr][tc + 3] = v.w;
    __syncthreads();
    bf16x4 o;
    o[0] = (__bf16)t[tc + 0][tr];
    o[1] = (__bf16)t[tc + 1][tr];
    o[2] = (__bf16)t[tc + 2][tr];
    o[3] = (__bf16)t[tc + 3][tr];
    *(bf16x4*)&dst[(size_t)(c0 + tr) * R + r0 + tc] = o;
}

// ---------------------------------------------------------------------------
// Gating: fp32 logits, softmax, top-2 (strict > keeps lowest index).
// ---------------------------------------------------------------------------
__global__ void gate_kernel(const float* __restrict__ x, const float* __restrict__ gW,
                            const float* __restrict__ gb, int* __restrict__ top_idx,
                            float* __restrict__ top_gate, int* __restrict__ cnt) {
    const int tokn = blockIdx.x * 4 + (threadIdx.x >> 6);
    const int lane = threadIdx.x & 63;
    const float* xr = x + (size_t)tokn * DIM;
    float acc[NE] = {};
    for (int i = 0; i < DIM / 64; i++) {
        const int d = lane + i * 64;
        const float xv = xr[d];
        const float4 w0 = *(const float4*)&gW[d * NE];
        const float4 w1 = *(const float4*)&gW[d * NE + 4];
        acc[0] += xv * w0.x; acc[1] += xv * w0.y; acc[2] += xv * w0.z; acc[3] += xv * w0.w;
        acc[4] += xv * w1.x; acc[5] += xv * w1.y; acc[6] += xv * w1.z; acc[7] += xv * w1.w;
    }
#pragma unroll
    for (int e = 0; e < NE; e++)
#pragma unroll
        for (int s = 32; s > 0; s >>= 1)
            acc[e] += __shfl_down(acc[e], s, 64);
    if (lane == 0) {
        float lg[NE], p[NE];
        float mx = -1e30f;
#pragma unroll
        for (int e = 0; e < NE; e++) { lg[e] = acc[e] + gb[e]; mx = fmaxf(mx, lg[e]); }
        float s = 0.f;
#pragma unroll
        for (int e = 0; e < NE; e++) { p[e] = __expf(lg[e] - mx); s += p[e]; }
        const float inv = 1.f / s;
#pragma unroll
        for (int e = 0; e < NE; e++) p[e] *= inv;
        int i0 = 0; float p0 = p[0];
#pragma unroll
        for (int e = 1; e < NE; e++) if (p[e] > p0) { p0 = p[e]; i0 = e; }
        int i1 = -1; float p1 = -1.f;
#pragma unroll
        for (int e = 0; e < NE; e++) if (e != i0 && p[e] > p1) { p1 = p[e]; i1 = e; }
        top_idx[tokn * 2] = i0;  top_idx[tokn * 2 + 1] = i1;
        top_gate[tokn * 2] = p0; top_gate[tokn * 2 + 1] = p1;
        atomicAdd(&cnt[i0], 1);  atomicAdd(&cnt[i1], 1);
    }
}

__global__ void scan_kernel(const int* __restrict__ cnt, int* __restrict__ offs) {
    if (threadIdx.x == 0) {
        int s = 0;
        for (int e = 0; e < NE; e++) { offs[e] = s; s += cnt[e]; }
        offs[NE] = s;
    }
}

__global__ void build_kernel(const int* __restrict__ top_idx, const int* __restrict__ offs,
                             int* __restrict__ run, int* __restrict__ row_token,
                             int* __restrict__ tok_row) {
    const int n = blockIdx.x * 256 + threadIdx.x;
    if (n >= N_TOK) return;
#pragma unroll
    for (int k = 0; k < 2; k++) {
        const int e = top_idx[n * 2 + k];
        const int pos = atomicAdd(&run[e], 1);
        const int r = offs[e] + pos;
        row_token[r] = n;
        tok_row[n * 2 + k] = r;
    }
}

// ---------------------------------------------------------------------------
// Grouped GEMM1: h[r] = relu(x[tok(r)] @ W1t[e] + b1[e]), bf16 out.
// 128x128 tile, BK=64, global_load_lds(16B), XOR-swizzled LDS (conflict-free).
// XCD-aware 1-D grid: lin = e + 8*(n0t*32 + mt)  =>  xcd ~= lin%8 = e.
//   Per XCD: one expert's x-rows (~2MB) + w1t[e] tiles, mt innermost so the
//   ~8 blocks sharing a B-tile are temporally adjacent on the same L2.
// ---------------------------------------------------------------------------
__global__ __launch_bounds__(256, 2) void gemm1_kernel(
    const __bf16* __restrict__ xb, const __bf16* __restrict__ w1t,
    const float* __restrict__ b1, const int* __restrict__ cnt,
    const int* __restrict__ offs, const int* __restrict__ row_token,
    __bf16* __restrict__ h) {
    const int lin = blockIdx.x;
    const int e   = lin & 7;
    const int t   = lin >> 3;
    const int mt  = t & 31;
    const int n0  = (t >> 5) * 128;
    const int ce  = cnt[e];
    if (mt * 128 >= ce) return;
    const int off_e = offs[e];

    __shared__ __bf16 lA[8192];   // 128 rows x 64 cols = 16KB, swizzled
    __shared__ __bf16 lB[8192];

    const int tid  = threadIdx.x;
    const int lane = tid & 63;
    const int wid  = tid >> 6;
    const int quad = lane >> 4;
    const int l16  = lane & 15;
    const int wm   = wid & 1;
    const int wn   = wid >> 1;

    // staging: DMA instr j (wave wid) covers rows (wid*4+j)*8 .. +7
    const int lrow = lane >> 3;              // row within 8-row group
    const int cch  = (lane & 7) ^ lrow;      // global 16B-chunk within row
    const __bf16* aros[4]; const __bf16* bros[4];
    char* ldsA[4]; char* ldsB[4];
#pragma unroll
    for (int j = 0; j < 4; j++) {
        const int row = (wid * 4 + j) * 8 + lrow;     // tile row 0..127
        int gr = off_e + mt * 128 + row;
        gr = gr < 2 * N_TOK - 1 ? gr : 2 * N_TOK - 1;
        const int tok = row_token[gr] & (N_TOK - 1);
        aros[j] = xb  + (size_t)tok * DIM + cch * 8;
        bros[j] = w1t + ((size_t)e * HID + n0 + row) * DIM + cch * 8;
        ldsA[j] = (char*)lA + (wid * 4 + j) * 1024;
        ldsB[j] = (char*)lB + (wid * 4 + j) * 1024;
    }

    f32x4 acc[4][4] = {};

    for (int kk = 0; kk < DIM; kk += 64) {
#pragma unroll
        for (int j = 0; j < 4; j++) gload16(aros[j] + kk, ldsA[j]);
#pragma unroll
        for (int j = 0; j < 4; j++) gload16(bros[j] + kk, ldsB[j]);
        __syncthreads();
#pragma unroll
        for (int hh = 0; hh < 2; hh++) {
            const int q4 = quad + hh * 4;
            const int sw = (q4 ^ (l16 & 7)) << 4;
            bf16x8 af[4], bfr[4];
#pragma unroll
            for (int mi = 0; mi < 4; mi++) {
                const int ar = wm * 64 + mi * 16 + l16;
                af[mi] = *(const bf16x8*)((const char*)lA + ar * 128 + sw);
            }
#pragma unroll
            for (int ni = 0; ni < 4; ni++) {
                const int br = wn * 64 + ni * 16 + l16;
                bfr[ni] = *(const bf16x8*)((const char*)lB + br * 128 + sw);
            }
#pragma unroll
            for (int mi = 0; mi < 4; mi++)
#pragma unroll
                for (int ni = 0; ni < 4; ni++)
                    acc[mi][ni] = __builtin_amdgcn_mfma_f32_16x16x32_bf16(af[mi], bfr[ni], acc[mi][ni], 0, 0, 0);
        }
        __syncthreads();
    }

#pragma unroll
    for (int ni = 0; ni < 4; ni++) {
        const int col = n0 + wn * 64 + ni * 16 + l16;
        const float bias = b1[e * HID + col];
#pragma unroll
        for (int mi = 0; mi < 4; mi++) {
#pragma unroll
            for (int r = 0; r < 4; r++) {
                const int lr = wm * 64 + mi * 16 + quad * 4 + r;
                const int gm = mt * 128 + lr;
                if (gm < ce) {
                    float v = acc[mi][ni][r] + bias;
                    v = v > 0.f ? v : 0.f;
                    h[(size_t)(off_e + gm) * HID + col] = (__bf16)v;
                }
            }
        }
    }
}

// ---------------------------------------------------------------------------
// Grouped GEMM2: y[r] = h[r] @ W2t[e] + b2[e], fp32 out (no atomics).
// Same structure; XCD-aware grid lin = e + 8*(n0t*32 + mt).
// ---------------------------------------------------------------------------
__global__ __launch_bounds__(256, 2) void gemm2_kernel(
    const __bf16* __restrict__ h, const __bf16* __restrict__ w2t,
    const float* __restrict__ b2, const int* __restrict__ cnt,
    const int* __restrict__ offs, float* __restrict__ y) {
    const int lin = blockIdx.x;
    const int e   = lin & 7;
    const int t   = lin >> 3;
    const int mt  = t & 31;
    const int n0  = (t >> 5) * 128;
    const int ce  = cnt[e];
    if (mt * 128 >= ce) return;
    const int off_e = offs[e];

    __shared__ __bf16 lA[8192];
    __shared__ __bf16 lB[8192];

    const int tid  = threadIdx.x;
    const int lane = tid & 63;
    const int wid  = tid >> 6;
    const int quad = lane >> 4;
    const int l16  = lane & 15;
    const int wm   = wid & 1;
    const int wn   = wid >> 1;

    const int lrow = lane >> 3;
    const int cch  = (lane & 7) ^ lrow;
    const __bf16* aros[4]; const __bf16* bros[4];
    char* ldsA[4]; char* ldsB[4];
#pragma unroll
    for (int j = 0; j < 4; j++) {
        const int row = (wid * 4 + j) * 8 + lrow;
        int gr = off_e + mt * 128 + row;
        gr = gr < 2 * N_TOK - 1 ? gr : 2 * N_TOK - 1;   // clamp inside h buffer
        aros[j] = h   + (size_t)gr * HID + cch * 8;
        bros[j] = w2t + ((size_t)e * DIM + n0 + row) * HID + cch * 8;
        ldsA[j] = (char*)lA + (wid * 4 + j) * 1024;
        ldsB[j] = (char*)lB + (wid * 4 + j) * 1024;
    }

    f32x4 acc[4][4] = {};

    for (int kk = 0; kk < HID; kk += 64) {
#pragma unroll
        for (int j = 0; j < 4; j++) gload16(aros[j] + kk, ldsA[j]);
#pragma unroll
        for (int j = 0; j < 4; j++) gload16(bros[j] + kk, ldsB[j]);
        __syncthreads();
#pragma unroll
        for (int hh = 0; hh < 2; hh++) {
            const int q4 = quad + hh * 4;
            const int sw = (q4 ^ (l16 & 7)) << 4;
            bf16x8 af[4], bfr[4];
#pragma unroll
            for (int mi = 0; mi < 4; mi++) {
                const int ar = wm * 64 + mi * 16 + l16;
                af[mi] = *(const bf16x8*)((const char*)lA + ar * 128 + sw);
            }
#pragma unroll
            for (int ni = 0; ni < 4; ni++) {
                const int br = wn * 64 + ni * 16 + l16;
                bfr[ni] = *(const bf16x8*)((const char*)lB + br * 128 + sw);
            }
#pragma unroll
            for (int mi = 0; mi < 4; mi++)
#pragma unroll
                for (int ni = 0; ni < 4; ni++)
                    acc[mi][ni] = __builtin_amdgcn_mfma_f32_16x16x32_bf16(af[mi], bfr[ni], acc[mi][ni], 0, 0, 0);
        }
        __syncthreads();
    }

#pragma unroll
    for (int mi = 0; mi < 4; mi++) {
#pragma unroll
        for (int r = 0; r < 4; r++) {
            const int lr = wm * 64 + mi * 16 + quad * 4 + r;
            const int gm = mt * 128 + lr;
            if (gm < ce) {
#pragma unroll
                for (int ni = 0; ni < 4; ni++) {
                    const int col = n0 + wn * 64 + ni * 16 + l16;
                    y[(size_t)(off_e + gm) * DIM + col] = acc[mi][ni][r] + b2[e * DIM + col];
                }
            }
        }
    }
}

// out[n] = g0*y[r0] + g1*y[r1] — coalesced, one block per token row.
__global__ void combine_kernel(const float* __restrict__ y, const int* __restrict__ tok_row,
                               const float* __restrict__ top_gate, float* __restrict__ out) {
    const int n = blockIdx.x;
    const int d = threadIdx.x * 4;
    const int r0 = tok_row[n * 2], r1 = tok_row[n * 2 + 1];
    const float g0 = top_gate[n * 2], g1 = top_gate[n * 2 + 1];
    float4 a = *(const float4*)&y[(size_t)r0 * DIM + d];
    float4 b = *(const float4*)&y[(size_t)r1 * DIM + d];
    float4 o = { g0 * a.x + g1 * b.x, g0 * a.y + g1 * b.y,
                 g0 * a.z + g1 * b.z, g0 * a.w + g1 * b.w };
    *(float4*)&out[(size_t)n * DIM + d] = o;
}

// ---------------------------------------------------------------------------
extern "C" void kernel_launch(void* const* d_in, const int* in_sizes, int n_in,
                              void* d_out, int out_size, void* d_ws, size_t ws_size,
                              hipStream_t stream) {
    const float* x  = (const float*)d_in[0];
    const float* gW = (const float*)d_in[1];
    const float* gb = (const float*)d_in[2];
    const float* W1 = (const float*)d_in[3];
    const float* b1 = (const float*)d_in[4];
    const float* W2 = (const float*)d_in[5];
    const float* b2 = (const float*)d_in[6];
    float* out = (float*)d_out;

    char* ws = (char*)d_ws;
    // ws layout:
    //   [0, 8 MiB)    xb  : x bf16 [N][D]
    //   [8, 40 MiB)   w1t : W1^T bf16 [E][H][D]   (dead after gemm1)
    //   [8, 40 MiB)   y   : fp32 [2N][D]          (overlays w1t)
    //   [40, 72 MiB)  w2t : W2^T bf16 [E][D][H]
    //   [72, 104 MiB) h   : bf16 [2N][H]
    //   [104 MiB..)   routing metadata
    __bf16* xb   = (__bf16*)(ws);
    __bf16* w1t  = (__bf16*)(ws + ((size_t)8  << 20));
    float*  ybuf = (float*) (ws + ((size_t)8  << 20));
    __bf16* w2t  = (__bf16*)(ws + ((size_t)40 << 20));
    __bf16* hbuf = (__bf16*)(ws + ((size_t)72 << 20));
    char* tail   = ws + ((size_t)104 << 20);
    int*   row_token = (int*)(tail);
    int*   tok_row   = (int*)(tail + 32768);
    int*   top_idx   = (int*)(tail + 65536);
    float* top_gate  = (float*)(tail + 98304);
    int*   cnt       = (int*)(tail + 131072);
    int*   offs      = cnt + 16;
    int*   run       = cnt + 32;

    hipMemsetAsync(cnt, 0, 256, stream);

    cvt_x_kernel<<<N_TOK * DIM / 4 / 256, 256, 0, stream>>>(x, xb);
    transpose_cvt_kernel<<<dim3(DIM / 32, HID / 32, NE), 256, 0, stream>>>(W1, w1t, DIM, HID);
    transpose_cvt_kernel<<<dim3(HID / 32, DIM / 32, NE), 256, 0, stream>>>(W2, w2t, HID, DIM);
    gate_kernel<<<N_TOK / 4, 256, 0, stream>>>(x, gW, gb, top_idx, top_gate, cnt);
    scan_kernel<<<1, 64, 0, stream>>>(cnt, offs);
    build_kernel<<<N_TOK / 256, 256, 0, stream>>>(top_idx, offs, run, row_token, tok_row);
    // XCD-aware 1-D grids: lin = e + 8*(n0t*32 + mt)
    gemm1_kernel<<<NE * 32 * (HID / 128), 256, 0, stream>>>(xb, w1t, b1, cnt, offs, row_token, hbuf);
    gemm2_kernel<<<NE * 32 * (DIM / 128), 256, 0, stream>>>(hbuf, w2t, b2, cnt, offs, ybuf);
    combine_kernel<<<N_TOK, 256, 0, stream>>>(ybuf, tok_row, top_gate, out);
}

// Round 5
// 327.432 us; speedup vs baseline: 2.7189x; 1.3159x over previous
//
#include <hip/hip_runtime.h>
#include <hip/hip_bf16.h>
#include <cstdint>

// Problem constants: N=4096 tokens, D=1024, H=2048, E=8, TOP_K=2
#define N_TOK 4096
#define DIM   1024
#define HID   2048
#define NE    8

typedef __bf16 bf16x8 __attribute__((ext_vector_type(8)));
typedef __bf16 bf16x4 __attribute__((ext_vector_type(4)));
typedef float  f32x4  __attribute__((ext_vector_type(4)));

// Async global->LDS DMA, 16B/lane. LDS dest = wave-uniform base + lane*16.
__device__ __forceinline__ void gload16(const void* g, void* l) {
    __builtin_amdgcn_global_load_lds(
        (const __attribute__((address_space(1))) void*)g,
        (__attribute__((address_space(3))) void*)l, 16, 0, 0);
}

// ---------------------------------------------------------------------------
// x fp32 -> bf16
// ---------------------------------------------------------------------------
__global__ void cvt_x_kernel(const float* __restrict__ x, __bf16* __restrict__ xb) {
    const int i = (blockIdx.x * 256 + threadIdx.x) * 4;
    float4 v = *(const float4*)&x[i];
    bf16x4 o = { (__bf16)v.x, (__bf16)v.y, (__bf16)v.z, (__bf16)v.w };
    *(bf16x4*)&xb[i] = o;
}

// ---------------------------------------------------------------------------
// Per-expert transpose + fp32->bf16: src [E][R][C] -> dst [E][C][R]
// ---------------------------------------------------------------------------
__global__ void transpose_cvt_kernel(const float* __restrict__ src, __bf16* __restrict__ dst,
                                     int R, int C) {
    const size_t eoff = (size_t)blockIdx.z * R * C;
    src += eoff; dst += eoff;
    __shared__ float t[32][33];
    const int r0 = blockIdx.x * 32, c0 = blockIdx.y * 32;
    const int tr = threadIdx.x >> 3;
    const int tc = (threadIdx.x & 7) * 4;
    float4 v = *(const float4*)&src[(size_t)(r0 + tr) * C + c0 + tc];
    t[tr][tc + 0] = v.x; t[tr][tc + 1] = v.y; t[tr][tc + 2] = v.z; t[tr][tc + 3] = v.w;
    __syncthreads();
    bf16x4 o;
    o[0] = (__bf16)t[tc + 0][tr];
    o[1] = (__bf16)t[tc + 1][tr];
    o[2] = (__bf16)t[tc + 2][tr];
    o[3] = (__bf16)t[tc + 3][tr];
    *(bf16x4*)&dst[(size_t)(c0 + tr) * R + r0 + tc] = o;
}

// ---------------------------------------------------------------------------
// Gating: fp32 logits, softmax, top-2 (strict > keeps lowest index).
// One wave per token, float4 x loads for ILP. NO ATOMICS (counts done later).
// ---------------------------------------------------------------------------
__global__ void gate_kernel(const float* __restrict__ x, const float* __restrict__ gW,
                            const float* __restrict__ gb, int* __restrict__ top_idx,
                            float* __restrict__ top_gate) {
    const int tokn = blockIdx.x * 4 + (threadIdx.x >> 6);
    const int lane = threadIdx.x & 63;
    const float4* xr = (const float4*)(x + (size_t)tokn * DIM);
    float acc[NE] = {};
#pragma unroll
    for (int i = 0; i < 4; i++) {
        const int v4 = i * 64 + lane;            // float4 index 0..255
        const float4 xv = xr[v4];
        const float* wb = &gW[v4 * 4 * NE];      // 4 rows x 8 experts
        const float xs[4] = { xv.x, xv.y, xv.z, xv.w };
#pragma unroll
        for (int j = 0; j < 4; j++) {
            const float4 wa = *(const float4*)&wb[j * NE];
            const float4 wc = *(const float4*)&wb[j * NE + 4];
            acc[0] += xs[j] * wa.x; acc[1] += xs[j] * wa.y;
            acc[2] += xs[j] * wa.z; acc[3] += xs[j] * wa.w;
            acc[4] += xs[j] * wc.x; acc[5] += xs[j] * wc.y;
            acc[6] += xs[j] * wc.z; acc[7] += xs[j] * wc.w;
        }
    }
#pragma unroll
    for (int e = 0; e < NE; e++)
#pragma unroll
        for (int s = 32; s > 0; s >>= 1)
            acc[e] += __shfl_down(acc[e], s, 64);
    if (lane == 0) {
        float lg[NE], p[NE];
        float mx = -1e30f;
#pragma unroll
        for (int e = 0; e < NE; e++) { lg[e] = acc[e] + gb[e]; mx = fmaxf(mx, lg[e]); }
        float s = 0.f;
#pragma unroll
        for (int e = 0; e < NE; e++) { p[e] = __expf(lg[e] - mx); s += p[e]; }
        const float inv = 1.f / s;
#pragma unroll
        for (int e = 0; e < NE; e++) p[e] *= inv;
        int i0 = 0; float p0 = p[0];
#pragma unroll
        for (int e = 1; e < NE; e++) if (p[e] > p0) { p0 = p[e]; i0 = e; }
        int i1 = -1; float p1 = -1.f;
#pragma unroll
        for (int e = 0; e < NE; e++) if (e != i0 && p[e] > p1) { p1 = p[e]; i1 = e; }
        top_idx[tokn * 2] = i0;  top_idx[tokn * 2 + 1] = i1;
        top_gate[tokn * 2] = p0; top_gate[tokn * 2 + 1] = p1;
    }
}

// LDS histogram -> 8 global atomics per block (16 blocks => 128 total).
__global__ void count_kernel(const int* __restrict__ top_idx, int* __restrict__ cnt) {
    __shared__ int hist[NE];
    if (threadIdx.x < NE) hist[threadIdx.x] = 0;
    __syncthreads();
    const int n = blockIdx.x * 256 + threadIdx.x;
    atomicAdd(&hist[top_idx[n * 2]], 1);
    atomicAdd(&hist[top_idx[n * 2 + 1]], 1);
    __syncthreads();
    if (threadIdx.x < NE) atomicAdd(&cnt[threadIdx.x], hist[threadIdx.x]);
}

__global__ void scan_kernel(const int* __restrict__ cnt, int* __restrict__ offs) {
    if (threadIdx.x == 0) {
        int s = 0;
        for (int e = 0; e < NE; e++) { offs[e] = s; s += cnt[e]; }
        offs[NE] = s;
    }
}

// Row assignment: LDS ranks + one global atomic per (block, expert).
__global__ void build_kernel(const int* __restrict__ top_idx, const int* __restrict__ offs,
                             int* __restrict__ run, int* __restrict__ row_token,
                             int* __restrict__ tok_row) {
    __shared__ int lrun[NE];
    __shared__ int base[NE];
    if (threadIdx.x < NE) lrun[threadIdx.x] = 0;
    __syncthreads();
    const int n = blockIdx.x * 256 + threadIdx.x;
    const int e0 = top_idx[n * 2], e1 = top_idx[n * 2 + 1];
    const int p0 = atomicAdd(&lrun[e0], 1);
    const int p1 = atomicAdd(&lrun[e1], 1);
    __syncthreads();
    if (threadIdx.x < NE) base[threadIdx.x] = atomicAdd(&run[threadIdx.x], lrun[threadIdx.x]);
    __syncthreads();
    const int r0 = offs[e0] + base[e0] + p0;
    const int r1 = offs[e1] + base[e1] + p1;
    row_token[r0] = n; tok_row[n * 2] = r0;
    row_token[r1] = n; tok_row[n * 2 + 1] = r1;
}

// ---------------------------------------------------------------------------
// Grouped GEMM1: h[r] = relu(x[tok(r)] @ W1t[e] + b1[e]), bf16 out.
// 128x128 tile, BK=64, global_load_lds(16B), XOR-swizzled LDS (conflict-free).
// XCD-aware 1-D grid: lin = e + 8*(n0t*32 + mt)  =>  xcd ~= lin%8 = e.
// ---------------------------------------------------------------------------
__global__ __launch_bounds__(256, 2) void gemm1_kernel(
    const __bf16* __restrict__ xb, const __bf16* __restrict__ w1t,
    const float* __restrict__ b1, const int* __restrict__ cnt,
    const int* __restrict__ offs, const int* __restrict__ row_token,
    __bf16* __restrict__ h) {
    const int lin = blockIdx.x;
    const int e   = lin & 7;
    const int t   = lin >> 3;
    const int mt  = t & 31;
    const int n0  = (t >> 5) * 128;
    const int ce  = cnt[e];
    if (mt * 128 >= ce) return;
    const int off_e = offs[e];

    __shared__ __bf16 lA[8192];   // 128 rows x 64 cols = 16KB, swizzled
    __shared__ __bf16 lB[8192];

    const int tid  = threadIdx.x;
    const int lane = tid & 63;
    const int wid  = tid >> 6;
    const int quad = lane >> 4;
    const int l16  = lane & 15;
    const int wm   = wid & 1;
    const int wn   = wid >> 1;

    const int lrow = lane >> 3;              // row within 8-row group
    const int cch  = (lane & 7) ^ lrow;      // global 16B-chunk within row
    const __bf16* aros[4]; const __bf16* bros[4];
    char* ldsA[4]; char* ldsB[4];
#pragma unroll
    for (int j = 0; j < 4; j++) {
        const int row = (wid * 4 + j) * 8 + lrow;     // tile row 0..127
        int gr = off_e + mt * 128 + row;
        gr = gr < 2 * N_TOK - 1 ? gr : 2 * N_TOK - 1;
        const int tok = row_token[gr] & (N_TOK - 1);
        aros[j] = xb  + (size_t)tok * DIM + cch * 8;
        bros[j] = w1t + ((size_t)e * HID + n0 + row) * DIM + cch * 8;
        ldsA[j] = (char*)lA + (wid * 4 + j) * 1024;
        ldsB[j] = (char*)lB + (wid * 4 + j) * 1024;
    }

    f32x4 acc[4][4] = {};

    for (int kk = 0; kk < DIM; kk += 64) {
#pragma unroll
        for (int j = 0; j < 4; j++) gload16(aros[j] + kk, ldsA[j]);
#pragma unroll
        for (int j = 0; j < 4; j++) gload16(bros[j] + kk, ldsB[j]);
        __syncthreads();
#pragma unroll
        for (int hh = 0; hh < 2; hh++) {
            const int q4 = quad + hh * 4;
            const int sw = (q4 ^ (l16 & 7)) << 4;
            bf16x8 af[4], bfr[4];
#pragma unroll
            for (int mi = 0; mi < 4; mi++) {
                const int ar = wm * 64 + mi * 16 + l16;
                af[mi] = *(const bf16x8*)((const char*)lA + ar * 128 + sw);
            }
#pragma unroll
            for (int ni = 0; ni < 4; ni++) {
                const int br = wn * 64 + ni * 16 + l16;
                bfr[ni] = *(const bf16x8*)((const char*)lB + br * 128 + sw);
            }
#pragma unroll
            for (int mi = 0; mi < 4; mi++)
#pragma unroll
                for (int ni = 0; ni < 4; ni++)
                    acc[mi][ni] = __builtin_amdgcn_mfma_f32_16x16x32_bf16(af[mi], bfr[ni], acc[mi][ni], 0, 0, 0);
        }
        __syncthreads();
    }

#pragma unroll
    for (int ni = 0; ni < 4; ni++) {
        const int col = n0 + wn * 64 + ni * 16 + l16;
        const float bias = b1[e * HID + col];
#pragma unroll
        for (int mi = 0; mi < 4; mi++) {
#pragma unroll
            for (int r = 0; r < 4; r++) {
                const int lr = wm * 64 + mi * 16 + quad * 4 + r;
                const int gm = mt * 128 + lr;
                if (gm < ce) {
                    float v = acc[mi][ni][r] + bias;
                    v = v > 0.f ? v : 0.f;
                    h[(size_t)(off_e + gm) * HID + col] = (__bf16)v;
                }
            }
        }
    }
}

// ---------------------------------------------------------------------------
// Grouped GEMM2: y[r] = h[r] @ W2t[e] + b2[e], fp32 out (no atomics).
// ---------------------------------------------------------------------------
__global__ __launch_bounds__(256, 2) void gemm2_kernel(
    const __bf16* __restrict__ h, const __bf16* __restrict__ w2t,
    const float* __restrict__ b2, const int* __restrict__ cnt,
    const int* __restrict__ offs, float* __restrict__ y) {
    const int lin = blockIdx.x;
    const int e   = lin & 7;
    const int t   = lin >> 3;
    const int mt  = t & 31;
    const int n0  = (t >> 5) * 128;
    const int ce  = cnt[e];
    if (mt * 128 >= ce) return;
    const int off_e = offs[e];

    __shared__ __bf16 lA[8192];
    __shared__ __bf16 lB[8192];

    const int tid  = threadIdx.x;
    const int lane = tid & 63;
    const int wid  = tid >> 6;
    const int quad = lane >> 4;
    const int l16  = lane & 15;
    const int wm   = wid & 1;
    const int wn   = wid >> 1;

    const int lrow = lane >> 3;
    const int cch  = (lane & 7) ^ lrow;
    const __bf16* aros[4]; const __bf16* bros[4];
    char* ldsA[4]; char* ldsB[4];
#pragma unroll
    for (int j = 0; j < 4; j++) {
        const int row = (wid * 4 + j) * 8 + lrow;
        int gr = off_e + mt * 128 + row;
        gr = gr < 2 * N_TOK - 1 ? gr : 2 * N_TOK - 1;   // clamp inside h buffer
        aros[j] = h   + (size_t)gr * HID + cch * 8;
        bros[j] = w2t + ((size_t)e * DIM + n0 + row) * HID + cch * 8;
        ldsA[j] = (char*)lA + (wid * 4 + j) * 1024;
        ldsB[j] = (char*)lB + (wid * 4 + j) * 1024;
    }

    f32x4 acc[4][4] = {};

    for (int kk = 0; kk < HID; kk += 64) {
#pragma unroll
        for (int j = 0; j < 4; j++) gload16(aros[j] + kk, ldsA[j]);
#pragma unroll
        for (int j = 0; j < 4; j++) gload16(bros[j] + kk, ldsB[j]);
        __syncthreads();
#pragma unroll
        for (int hh = 0; hh < 2; hh++) {
            const int q4 = quad + hh * 4;
            const int sw = (q4 ^ (l16 & 7)) << 4;
            bf16x8 af[4], bfr[4];
#pragma unroll
            for (int mi = 0; mi < 4; mi++) {
                const int ar = wm * 64 + mi * 16 + l16;
                af[mi] = *(const bf16x8*)((const char*)lA + ar * 128 + sw);
            }
#pragma unroll
            for (int ni = 0; ni < 4; ni++) {
                const int br = wn * 64 + ni * 16 + l16;
                bfr[ni] = *(const bf16x8*)((const char*)lB + br * 128 + sw);
            }
#pragma unroll
            for (int mi = 0; mi < 4; mi++)
#pragma unroll
                for (int ni = 0; ni < 4; ni++)
                    acc[mi][ni] = __builtin_amdgcn_mfma_f32_16x16x32_bf16(af[mi], bfr[ni], acc[mi][ni], 0, 0, 0);
        }
        __syncthreads();
    }

#pragma unroll
    for (int mi = 0; mi < 4; mi++) {
#pragma unroll
        for (int r = 0; r < 4; r++) {
            const int lr = wm * 64 + mi * 16 + quad * 4 + r;
            const int gm = mt * 128 + lr;
            if (gm < ce) {
#pragma unroll
                for (int ni = 0; ni < 4; ni++) {
                    const int col = n0 + wn * 64 + ni * 16 + l16;
                    y[(size_t)(off_e + gm) * DIM + col] = acc[mi][ni][r] + b2[e * DIM + col];
                }
            }
        }
    }
}

// out[n] = g0*y[r0] + g1*y[r1] — coalesced, one block per token row.
__global__ void combine_kernel(const float* __restrict__ y, const int* __restrict__ tok_row,
                               const float* __restrict__ top_gate, float* __restrict__ out) {
    const int n = blockIdx.x;
    const int d = threadIdx.x * 4;
    const int r0 = tok_row[n * 2], r1 = tok_row[n * 2 + 1];
    const float g0 = top_gate[n * 2], g1 = top_gate[n * 2 + 1];
    float4 a = *(const float4*)&y[(size_t)r0 * DIM + d];
    float4 b = *(const float4*)&y[(size_t)r1 * DIM + d];
    float4 o = { g0 * a.x + g1 * b.x, g0 * a.y + g1 * b.y,
                 g0 * a.z + g1 * b.z, g0 * a.w + g1 * b.w };
    *(float4*)&out[(size_t)n * DIM + d] = o;
}

// ---------------------------------------------------------------------------
extern "C" void kernel_launch(void* const* d_in, const int* in_sizes, int n_in,
                              void* d_out, int out_size, void* d_ws, size_t ws_size,
                              hipStream_t stream) {
    const float* x  = (const float*)d_in[0];
    const float* gW = (const float*)d_in[1];
    const float* gb = (const float*)d_in[2];
    const float* W1 = (const float*)d_in[3];
    const float* b1 = (const float*)d_in[4];
    const float* W2 = (const float*)d_in[5];
    const float* b2 = (const float*)d_in[6];
    float* out = (float*)d_out;

    char* ws = (char*)d_ws;
    // ws layout:
    //   [0, 8 MiB)    xb  : x bf16 [N][D]
    //   [8, 40 MiB)   w1t : W1^T bf16 [E][H][D]   (dead after gemm1)
    //   [8, 40 MiB)   y   : fp32 [2N][D]          (overlays w1t)
    //   [40, 72 MiB)  w2t : W2^T bf16 [E][D][H]
    //   [72, 104 MiB) h   : bf16 [2N][H]
    //   [104 MiB..)   routing metadata
    __bf16* xb   = (__bf16*)(ws);
    __bf16* w1t  = (__bf16*)(ws + ((size_t)8  << 20));
    float*  ybuf = (float*) (ws + ((size_t)8  << 20));
    __bf16* w2t  = (__bf16*)(ws + ((size_t)40 << 20));
    __bf16* hbuf = (__bf16*)(ws + ((size_t)72 << 20));
    char* tail   = ws + ((size_t)104 << 20);
    int*   row_token = (int*)(tail);
    int*   tok_row   = (int*)(tail + 32768);
    int*   top_idx   = (int*)(tail + 65536);
    float* top_gate  = (float*)(tail + 98304);
    int*   cnt       = (int*)(tail + 131072);
    int*   offs      = cnt + 16;
    int*   run       = cnt + 32;

    hipMemsetAsync(cnt, 0, 256, stream);

    cvt_x_kernel<<<N_TOK * DIM / 4 / 256, 256, 0, stream>>>(x, xb);
    transpose_cvt_kernel<<<dim3(DIM / 32, HID / 32, NE), 256, 0, stream>>>(W1, w1t, DIM, HID);
    transpose_cvt_kernel<<<dim3(HID / 32, DIM / 32, NE), 256, 0, stream>>>(W2, w2t, HID, DIM);
    gate_kernel<<<N_TOK / 4, 256, 0, stream>>>(x, gW, gb, top_idx, top_gate);
    count_kernel<<<N_TOK / 256, 256, 0, stream>>>(top_idx, cnt);
    scan_kernel<<<1, 64, 0, stream>>>(cnt, offs);
    build_kernel<<<N_TOK / 256, 256, 0, stream>>>(top_idx, offs, run, row_token, tok_row);
    // XCD-aware 1-D grids: lin = e + 8*(n0t*32 + mt)
    gemm1_kernel<<<NE * 32 * (HID / 128), 256, 0, stream>>>(xb, w1t, b1, cnt, offs, row_token, hbuf);
    gemm2_kernel<<<NE * 32 * (DIM / 128), 256, 0, stream>>>(hbuf, w2t, b2, cnt, offs, ybuf);
    combine_kernel<<<N_TOK, 256, 0, stream>>>(ybuf, tok_row, top_gate, out);
}